// Round 13
// baseline (474.890 us; speedup 1.0000x reference)
//
#include <hip/hip_runtime.h>
#include <hip/hip_bf16.h>
#include <stdint.h>

#define SEQ    2048
#define DMODEL 512
#define NPANEL 16
#define NORM   0.044194173824159216f  // 1/sqrt(512)

typedef _Float16 f16;
typedef __attribute__((ext_vector_type(8))) _Float16 half8;
typedef __attribute__((ext_vector_type(2))) _Float16 half2v;
typedef __attribute__((ext_vector_type(4))) float f32x4;
typedef __attribute__((ext_vector_type(4))) unsigned int u32x4;

__device__ __forceinline__ unsigned umin2(unsigned a, unsigned b){ return a<b?a:b; }
__device__ __forceinline__ unsigned umax2(unsigned a, unsigned b){ return a>b?a:b; }

// ---------------- K0a: x,y fp32 -> fp16 hi+lo planes ----------------
__global__ __launch_bounds__(256) void k_cvt(const float4* __restrict__ x,
                                             const float4* __restrict__ y,
                                             f16* __restrict__ xh, f16* __restrict__ xl,
                                             f16* __restrict__ yh, f16* __restrict__ yl){
  int i = blockIdx.x*256 + threadIdx.x;      // 524288 float4s per tensor
  float4 a = x[i]; float4 b = y[i];
  half2v h0 = {(f16)a.x, (f16)a.y}, h1 = {(f16)a.z, (f16)a.w};
  *(half2v*)(xh + i*4)     = h0; *(half2v*)(xh + i*4 + 2) = h1;
  half2v l0 = {(f16)(a.x-(float)h0[0]), (f16)(a.y-(float)h0[1])};
  half2v l1 = {(f16)(a.z-(float)h1[0]), (f16)(a.w-(float)h1[1])};
  *(half2v*)(xl + i*4)     = l0; *(half2v*)(xl + i*4 + 2) = l1;
  half2v g0 = {(f16)b.x, (f16)b.y}, g1 = {(f16)b.z, (f16)b.w};
  *(half2v*)(yh + i*4)     = g0; *(half2v*)(yh + i*4 + 2) = g1;
  half2v m0 = {(f16)(b.x-(float)g0[0]), (f16)(b.y-(float)g0[1])};
  half2v m1 = {(f16)(b.z-(float)g1[0]), (f16)(b.w-(float)g1[1])};
  *(half2v*)(yl + i*4)     = m0; *(half2v*)(yl + i*4 + 2) = m1;
}

// ---------------- K0b: weights -> transposed fp16 hi+lo: Wt[z][n][k] ----------------
__global__ __launch_bounds__(256) void k_wt(const float* __restrict__ Wq, const float* __restrict__ Wk,
                                            const float* __restrict__ Wv, const float* __restrict__ Wo,
                                            f16* __restrict__ Wth, f16* __restrict__ Wtl){
  int z = blockIdx.z;
  const float* W = (z==0)?Wq:(z==1)?Wk:(z==2)?Wv:Wo;
  __shared__ float tile[64][65];
  int k0 = blockIdx.x*64, n0 = blockIdx.y*64;
  #pragma unroll
  for (int i = 0; i < 16; ++i){
    int s = threadIdx.x + i*256; int kl2 = s>>6, nl = s&63;
    tile[kl2][nl] = W[(k0+kl2)*512 + (n0+nl)];
  }
  __syncthreads();
  #pragma unroll
  for (int i = 0; i < 16; ++i){
    int s = threadIdx.x + i*256; int nl = s>>6, kl2 = s&63;
    float v = tile[kl2][nl];
    f16 h = (f16)v;
    int idx = z*262144 + (n0+nl)*512 + (k0+kl2);
    Wth[idx] = h;
    Wtl[idx] = (f16)(v - (float)h);
  }
}

// ---------------- GEMM: C[m,n] = A[m,:] @ Wt[n,:]^T + bias ----------------
template<int FINAL>
__global__ __launch_bounds__(256) void k_gemm(const f16* __restrict__ Ah0, const f16* __restrict__ Al0,
                                              const f16* __restrict__ Ah1, const f16* __restrict__ Al1,
                                              const f16* __restrict__ Wh, const f16* __restrict__ Wl,
                                              const float* __restrict__ b0, const float* __restrict__ b1,
                                              const float* __restrict__ b2,
                                              f16* __restrict__ Oq, float* __restrict__ Of){
  int z = blockIdx.z;
  const f16* A  = (z==0) ? Ah0 : Ah1;
  const f16* Alp= (z==0) ? Al0 : Al1;
  const f16* Bh = Wh + z*262144;
  const f16* Bl = Wl + z*262144;
  const float* bias = (z==0)?b0:(z==1)?b1:b2;
  const bool split = (FINAL==0) && (z<2);
  int m0 = blockIdx.x*128, n0 = blockIdx.y*128;

  __shared__ f16 Ahs[128][40], Bhs[128][40], Als[128][40], Bls[128][40];

  int t = threadIdx.x, l = t&63, w = t>>6;
  int wr = w>>1, wc = w&1;
  int lr = l&15, lk = l>>4;

  f32x4 acc[4][4];
  #pragma unroll
  for (int i=0;i<4;++i)
    #pragma unroll
    for (int j=0;j<4;++j) acc[i][j] = (f32x4){0.f,0.f,0.f,0.f};

  for (int ks = 0; ks < 16; ++ks){
    int k0 = ks*32;
    #pragma unroll
    for (int i = 0; i < 2; ++i){
      int s = t + i*256; int r = s>>2, kc = s&3;
      *(u32x4*)(&Ahs[r][kc*8]) = *(const u32x4*)(A   + (m0+r)*512 + k0 + kc*8);
      *(u32x4*)(&Bhs[r][kc*8]) = *(const u32x4*)(Bh  + (n0+r)*512 + k0 + kc*8);
      if (split){
        *(u32x4*)(&Als[r][kc*8]) = *(const u32x4*)(Alp + (m0+r)*512 + k0 + kc*8);
        *(u32x4*)(&Bls[r][kc*8]) = *(const u32x4*)(Bl  + (n0+r)*512 + k0 + kc*8);
      }
    }
    __syncthreads();
    half8 ah[4], bh2[4], al2[4], bl2[4];
    #pragma unroll
    for (int tm = 0; tm < 4; ++tm) ah[tm]  = *(const half8*)(&Ahs[wr*64 + tm*16 + lr][lk*8]);
    #pragma unroll
    for (int tn = 0; tn < 4; ++tn) bh2[tn] = *(const half8*)(&Bhs[wc*64 + tn*16 + lr][lk*8]);
    if (split){
      #pragma unroll
      for (int tm = 0; tm < 4; ++tm) al2[tm] = *(const half8*)(&Als[wr*64 + tm*16 + lr][lk*8]);
      #pragma unroll
      for (int tn = 0; tn < 4; ++tn) bl2[tn] = *(const half8*)(&Bls[wc*64 + tn*16 + lr][lk*8]);
    }
    #pragma unroll
    for (int tm = 0; tm < 4; ++tm)
      #pragma unroll
      for (int tn = 0; tn < 4; ++tn){
        acc[tm][tn] = __builtin_amdgcn_mfma_f32_16x16x32_f16(ah[tm], bh2[tn], acc[tm][tn], 0,0,0);
        if (split){
          acc[tm][tn] = __builtin_amdgcn_mfma_f32_16x16x32_f16(ah[tm], bl2[tn], acc[tm][tn], 0,0,0);
          acc[tm][tn] = __builtin_amdgcn_mfma_f32_16x16x32_f16(al2[tm], bh2[tn], acc[tm][tn], 0,0,0);
        }
      }
    __syncthreads();
  }

  #pragma unroll
  for (int tn = 0; tn < 4; ++tn){
    int n_g = n0 + wc*64 + tn*16 + lr;
    float bv = bias[n_g];
    #pragma unroll
    for (int tm = 0; tm < 4; ++tm){
      #pragma unroll
      for (int r = 0; r < 4; ++r){
        int m_g = m0 + wr*64 + tm*16 + lk*4 + r;
        float v = acc[tm][tn][r] + bv;
        size_t idx = (size_t)m_g*512 + n_g;
        if (FINAL){
          Of[idx] = v;
        } else if (z < 2){
          f16 h = (f16)v;
          Oq[(size_t)z*4194304 + idx] = h;
          Oq[(size_t)z*4194304 + 2097152 + idx] = (f16)(v - (float)h);
        } else {
          Oq[(size_t)4*2097152 + idx] = (f16)v;
        }
      }
    }
  }
}

// ---------------- K2: V panels [s][d] -> Vt [d][s] (fp16, bit-copy) ----------------
__global__ __launch_bounds__(256) void k_vt(const unsigned short* __restrict__ V, unsigned short* __restrict__ Vt){
  int p = blockIdx.y;
  int t = threadIdx.x;
  int d = t & 63, sc = t >> 6;
  int s0b = blockIdx.x*32 + sc*8;
  const unsigned short* Vp = V + p*131072;
  unsigned short* Vtp = Vt + p*131072;
  typedef __attribute__((ext_vector_type(8))) short short8;
  short8 vv;
  #pragma unroll
  for (int j = 0; j < 8; ++j) vv[j] = (short)Vp[(s0b + j)*64 + d];
  *(short8*)(Vtp + d*2048 + s0b) = vv;
}

// ---------------- K3: fused attention (round-11 body, phase-ablation template) ----------------
// V=0 full -> O.  V=1 QK only.  V=2 QK+selection.  V=3 full minus bisect.  V=4 QK+PV (no sel).
// Variants write live checksums to scr (DCE protection).
template<int V>
__global__ __launch_bounds__(512, 4) void k_attn(const f16* __restrict__ Qh, const f16* __restrict__ Ql,
                                                 const f16* __restrict__ Kh, const f16* __restrict__ Kl,
                                                 const f16* __restrict__ Vt, f16* __restrict__ O,
                                                 float* __restrict__ scr){
  extern __shared__ char scb[];            // 65536
  __shared__ float rzs[16];
  __shared__ float red[1024];
  int p = blockIdx.x, qt = blockIdx.y;     // panel fastest -> XCD affinity
  int s0 = qt*16;
  int bid = blockIdx.x*gridDim.y + blockIdx.y;
  const f16* Qhp = Qh + p*131072;
  const f16* Qlp = Ql + p*131072;
  const f16* Khp = Kh + p*131072;
  const f16* Klp = Kl + p*131072;
  const f16* Vtp = Vt + p*131072;
  int t = threadIdx.x, l = t&63, w = t>>6;
  int lr = l&15, lk = l>>4;

  half8 qh[2], ql[2];
  #pragma unroll
  for (int f = 0; f < 2; ++f){
    qh[f] = *(const half8*)(Qhp + (s0+lr)*64 + f*32 + lk*8);
    ql[f] = *(const half8*)(Qlp + (s0+lr)*64 + f*32 + lk*8);
  }

  // ---- Phase A: cols [w*128,+128) ----
  {
    const f16* Kbase = Khp + (w*128 + lr)*64 + lk*8;
    const f16* Lbase = Klp + (w*128 + lr)*64 + lk*8;
    #pragma unroll
    for (int bt = 0; bt < 2; ++bt){
      half8 kb0[4], kb1[4], lb0[4], lb1[4];
      #pragma unroll
      for (int i = 0; i < 4; ++i){
        const f16* ka = Kbase + (bt*4 + i)*1024;
        const f16* la = Lbase + (bt*4 + i)*1024;
        kb0[i] = *(const half8*)(ka);
        kb1[i] = *(const half8*)(ka + 32);
        lb0[i] = *(const half8*)(la);
        lb1[i] = *(const half8*)(la + 32);
      }
      #pragma unroll
      for (int i = 0; i < 4; ++i){
        f32x4 c1 = (f32x4){0.f,0.f,0.f,0.f};
        f32x4 c2 = (f32x4){0.f,0.f,0.f,0.f};
        f32x4 c3 = (f32x4){0.f,0.f,0.f,0.f};
        c1 = __builtin_amdgcn_mfma_f32_16x16x32_f16(qh[0], kb0[i], c1, 0,0,0);
        c2 = __builtin_amdgcn_mfma_f32_16x16x32_f16(qh[0], lb0[i], c2, 0,0,0);
        c3 = __builtin_amdgcn_mfma_f32_16x16x32_f16(ql[0], kb0[i], c3, 0,0,0);
        c1 = __builtin_amdgcn_mfma_f32_16x16x32_f16(qh[1], kb1[i], c1, 0,0,0);
        c2 = __builtin_amdgcn_mfma_f32_16x16x32_f16(qh[1], lb1[i], c2, 0,0,0);
        c3 = __builtin_amdgcn_mfma_f32_16x16x32_f16(ql[1], kb1[i], c3, 0,0,0);
        int n = w*128 + (bt*4 + i)*16 + lr;
        #pragma unroll
        for (int r = 0; r < 4; ++r){
          int row = lk*4 + r;
          *(float*)(scb + row*4096 + (((unsigned)(n*4)) ^ ((unsigned)(lk<<6)))) = c1[r] + c2[r] + c3[r];
        }
      }
    }
  }
  __syncthreads();

  // persist phase-A ordered uints for my two rows (2w, 2w+1)
  unsigned ovA0[16], ovA1[16];
  if constexpr (V != 4){
    int row0 = w*2;
    unsigned C = ((unsigned)((row0>>2)&3))<<6;
    const char* rb0 = scb + row0*4096;
    const char* rb1 = rb0 + 4096;
    #pragma unroll
    for (int j = 0; j < 16; ++j){
      unsigned off = (((unsigned)((l + j*64)*4)) ^ C);
      unsigned u0 = *(const unsigned*)(rb0 + off);
      unsigned u1 = *(const unsigned*)(rb1 + off);
      ovA0[j] = ((int)u0 < 0) ? ~u0 : (u0 | 0x80000000u);
      ovA1[j] = ((int)u1 < 0) ? ~u1 : (u1 | 0x80000000u);
    }
  }
  __syncthreads();

  // ---- Phase B: cols 1024 + [w*128,+128) ----
  {
    const f16* Kbase = Khp + (1024 + w*128 + lr)*64 + lk*8;
    const f16* Lbase = Klp + (1024 + w*128 + lr)*64 + lk*8;
    #pragma unroll
    for (int bt = 0; bt < 4; ++bt){
      half8 kb0[2], kb1[2], lb0[2], lb1[2];
      #pragma unroll
      for (int i = 0; i < 2; ++i){
        const f16* ka = Kbase + (bt*2 + i)*1024;
        const f16* la = Lbase + (bt*2 + i)*1024;
        kb0[i] = *(const half8*)(ka);
        kb1[i] = *(const half8*)(ka + 32);
        lb0[i] = *(const half8*)(la);
        lb1[i] = *(const half8*)(la + 32);
      }
      #pragma unroll
      for (int i = 0; i < 2; ++i){
        f32x4 c1 = (f32x4){0.f,0.f,0.f,0.f};
        f32x4 c2 = (f32x4){0.f,0.f,0.f,0.f};
        f32x4 c3 = (f32x4){0.f,0.f,0.f,0.f};
        c1 = __builtin_amdgcn_mfma_f32_16x16x32_f16(qh[0], kb0[i], c1, 0,0,0);
        c2 = __builtin_amdgcn_mfma_f32_16x16x32_f16(qh[0], lb0[i], c2, 0,0,0);
        c3 = __builtin_amdgcn_mfma_f32_16x16x32_f16(ql[0], kb0[i], c3, 0,0,0);
        c1 = __builtin_amdgcn_mfma_f32_16x16x32_f16(qh[1], kb1[i], c1, 0,0,0);
        c2 = __builtin_amdgcn_mfma_f32_16x16x32_f16(qh[1], lb1[i], c2, 0,0,0);
        c3 = __builtin_amdgcn_mfma_f32_16x16x32_f16(ql[1], kb1[i], c3, 0,0,0);
        int n = w*128 + (bt*2 + i)*16 + lr;
        #pragma unroll
        for (int r = 0; r < 4; ++r){
          int row = lk*4 + r;
          *(float*)(scb + row*4096 + (((unsigned)(n*4)) ^ ((unsigned)(lk<<6)))) = c1[r] + c2[r] + c3[r];
        }
      }
    }
  }
  __syncthreads();

  if constexpr (V == 1){
    // consume phase-B LDS + persisted regs, then exit
    unsigned chk = ovA0[0] ^ ovA1[15];
    int row0 = w*2;
    unsigned C = ((unsigned)((row0>>2)&3))<<6;
    const char* rb0 = scb + row0*4096;
    #pragma unroll
    for (int j = 0; j < 16; ++j)
      chk ^= *(const unsigned*)(rb0 + (((unsigned)((l + j*64)*4)) ^ C));
    scr[bid*512 + t] = __uint_as_float(chk);
    return;
  }

  if constexpr (V == 4){
    if (t < 16) rzs[t] = 1.f;
  }

  // ---- selection + softmax weights (wave w owns rows 2w, 2w+1) ----
  if constexpr (V != 4){
    #pragma unroll 1
    for (int rr = 0; rr < 2; ++rr){
      int row = w*2 + rr;
      const char* rb = scb + row*4096;
      unsigned C = ((unsigned)((row>>2)&3))<<6;
      unsigned o2[16];
      #pragma unroll
      for (int j = 0; j < 16; ++j){
        unsigned u = *(const unsigned*)(rb + (((unsigned)((l + j*64)*4)) ^ C));
        o2[j] = ((int)u < 0) ? ~u : (u | 0x80000000u);
      }
      unsigned umn = 0xFFFFFFFFu, umx = 0u;
      #pragma unroll
      for (int j = 0; j < 16; ++j){
        unsigned a = (rr==0) ? ovA0[j] : ovA1[j];
        umn = umin2(umn, umin2(a, o2[j]));
        umx = umax2(umax2(umx, a), o2[j]);
      }
      #pragma unroll
      for (int off2 = 1; off2 < 64; off2 <<= 1){
        umn = umin2(umn, (unsigned)__shfl_xor((int)umn, off2));
        umx = umax2(umx, (unsigned)__shfl_xor((int)umx, off2));
      }
      unsigned thr;
      if constexpr (V == 3){
        thr = umn + ((umx - umn) >> 1);   // zero probes (junk mask, cost model only)
      } else {
        unsigned L = umn, R = umx;
        #pragma unroll 1
        for (;;){
          if (L >= R){ thr = R; break; }
          unsigned mid = L + ((R - L) >> 1);
          int c = 0;
          #pragma unroll
          for (int j = 0; j < 16; ++j){
            unsigned a = (rr==0) ? ovA0[j] : ovA1[j];
            c += (int)__popcll(__ballot(a <= mid));
            c += (int)__popcll(__ballot(o2[j] <= mid));
          }
          if (c == 1024){ thr = mid; break; }
          if (c > 1024) R = mid; else L = mid + 1;
        }
      }
      unsigned bmx = (umx & 0x80000000u) ? (umx & 0x7FFFFFFFu) : ~umx;
      float mx = __uint_as_float(bmx);
      float zs = 0.f;
      unsigned g = ((unsigned)(row & 7)) << 4;
      char* pb = scb + row*4096;
      #pragma unroll
      for (int j = 0; j < 32; ++j){
        unsigned a = (j < 16) ? ((rr==0) ? ovA0[j] : ovA1[j]) : o2[j-16];
        unsigned b = (a & 0x80000000u) ? (a & 0x7FFFFFFFu) : ~a;
        float v = __uint_as_float(b);
        float wgt = (a <= thr) ? 0.f : __expf((v - mx) * NORM);
        zs += wgt;
        unsigned col = (unsigned)((j & 15)*64 + l + (j >> 4)*1024);
        *(f16*)(pb + ((col*2) ^ g)) = (f16)wgt;
      }
      #pragma unroll
      for (int off2 = 1; off2 < 64; off2 <<= 1) zs += __shfl_xor(zs, off2);
      if (l == 0) rzs[row] = 1.f / zs;
    }
  }
  __syncthreads();

  if constexpr (V == 2){
    scr[bid*512 + t] = rzs[t & 15];
    return;
  }

  // ---- PV: wave: oc = w&3, kh2 = w>>2; 8 batches of 4 kc ----
  int oc = w & 3, kh2 = w >> 2;
  const f16* vbase = Vtp + (oc*16 + lr)*2048 + kh2*1024 + lk*8;
  const char* pbase = scb + lr*4096;
  unsigned pswz = ((unsigned)(lr & 7)) << 4;
  f32x4 o0 = (f32x4){0.f,0.f,0.f,0.f};
  f32x4 o1 = (f32x4){0.f,0.f,0.f,0.f};
  #pragma unroll
  for (int kb2 = 0; kb2 < 8; ++kb2){
    half8 pa[4], vb[4];
    #pragma unroll
    for (int i = 0; i < 4; ++i){
      int kc = kb2*4 + i;
      pa[i] = *(const half8*)(pbase + (((unsigned)((kh2*1024 + kc*32 + lk*8)*2)) ^ pswz));
      vb[i] = *(const half8*)(vbase + kc*32);
    }
    o0 = __builtin_amdgcn_mfma_f32_16x16x32_f16(pa[0], vb[0], o0, 0,0,0);
    o1 = __builtin_amdgcn_mfma_f32_16x16x32_f16(pa[1], vb[1], o1, 0,0,0);
    o0 = __builtin_amdgcn_mfma_f32_16x16x32_f16(pa[2], vb[2], o0, 0,0,0);
    o1 = __builtin_amdgcn_mfma_f32_16x16x32_f16(pa[3], vb[3], o1, 0,0,0);
  }
  f32x4 oa;
  #pragma unroll
  for (int r = 0; r < 4; ++r) oa[r] = o0[r] + o1[r];
  if (kh2 == 1){
    #pragma unroll
    for (int r = 0; r < 4; ++r) red[oc*256 + (lk*4+r)*16 + lr] = oa[r];
  }
  __syncthreads();
  if (kh2 == 0){
    float accum = 0.f;
    #pragma unroll
    for (int r = 0; r < 4; ++r){
      int row = lk*4 + r;
      float v = (oa[r] + red[oc*256 + row*16 + lr]) * rzs[row];
      if constexpr (V == 0){
        O[p*131072 + (s0+row)*64 + oc*16 + lr] = (f16)v;
      } else {
        accum += v;
      }
    }
    if constexpr (V != 0) scr[bid*512 + t] = accum;
  }
}

// ---------------- host ----------------
extern "C" void kernel_launch(void* const* d_in, const int* in_sizes, int n_in,
                              void* d_out, int out_size, void* d_ws, size_t ws_size,
                              hipStream_t stream) {
  const float* x  = (const float*)d_in[0];
  const float* y  = (const float*)d_in[1];
  const float* Wq = (const float*)d_in[2];
  const float* bq = (const float*)d_in[3];
  const float* Wk = (const float*)d_in[4];
  const float* bk = (const float*)d_in[5];
  const float* Wv = (const float*)d_in[6];
  const float* bv = (const float*)d_in[7];
  const float* Wo = (const float*)d_in[8];
  const float* bo = (const float*)d_in[9];

  f16* ws = (f16*)d_ws;
  f16* xh  = ws;                    // 2097152 each
  f16* xl  = ws + 2097152;
  f16* yh  = ws + 4194304;
  f16* yl  = ws + 6291456;
  f16* Wth = ws + 8388608;          // 4 x 262144
  f16* Wtl = ws + 9437184;
  f16* QKV = ws + 10485760;         // Qh,Ql,Kh,Kl,Vh : 5 x 2097152
  f16* Vt  = ws;                    // alias xh (dead after QKV gemm)
  f16* Ob  = ws + 2097152;          // alias xl (dead after QKV gemm)
  float* scr = (float*)((char*)d_ws + 41943040ULL);   // 1MB ablation scratch (spare region)

  (void)hipFuncSetAttribute(reinterpret_cast<const void*>(k_attn<0>), hipFuncAttributeMaxDynamicSharedMemorySize, 65536);
  (void)hipFuncSetAttribute(reinterpret_cast<const void*>(k_attn<1>), hipFuncAttributeMaxDynamicSharedMemorySize, 65536);
  (void)hipFuncSetAttribute(reinterpret_cast<const void*>(k_attn<2>), hipFuncAttributeMaxDynamicSharedMemorySize, 65536);
  (void)hipFuncSetAttribute(reinterpret_cast<const void*>(k_attn<3>), hipFuncAttributeMaxDynamicSharedMemorySize, 65536);
  (void)hipFuncSetAttribute(reinterpret_cast<const void*>(k_attn<4>), hipFuncAttributeMaxDynamicSharedMemorySize, 65536);

  k_cvt<<<2048, 256, 0, stream>>>((const float4*)x, (const float4*)y, xh, xl, yh, yl);
  k_wt<<<dim3(8,8,4), 256, 0, stream>>>(Wq, Wk, Wv, Wo, Wth, Wtl);
  k_gemm<0><<<dim3(32,4,3), 256, 0, stream>>>(xh, xl, yh, yl, Wth, Wtl, bq, bk, bv, QKV, nullptr);
  k_vt<<<dim3(64,16), 256, 0, stream>>>((const unsigned short*)(QKV + 4*2097152), (unsigned short*)Vt);

  // ---- ablation probes: quarter grid (one residency round), scratch output ----
  k_attn<1><<<dim3(16,32), 512, 65536, stream>>>(QKV, QKV + 2097152, QKV + 2*2097152, QKV + 3*2097152, Vt, Ob, scr);
  k_attn<2><<<dim3(16,32), 512, 65536, stream>>>(QKV, QKV + 2097152, QKV + 2*2097152, QKV + 3*2097152, Vt, Ob, scr);
  k_attn<3><<<dim3(16,32), 512, 65536, stream>>>(QKV, QKV + 2097152, QKV + 2*2097152, QKV + 3*2097152, Vt, Ob, scr);
  k_attn<4><<<dim3(16,32), 512, 65536, stream>>>(QKV, QKV + 2097152, QKV + 2*2097152, QKV + 3*2097152, Vt, Ob, scr);

  // ---- the real kernel ----
  k_attn<0><<<dim3(16,128), 512, 65536, stream>>>(QKV, QKV + 2097152, QKV + 2*2097152, QKV + 3*2097152, Vt, Ob, scr);

  k_gemm<1><<<dim3(32,4,1), 256, 0, stream>>>(Ob, Ob, Ob, Ob, Wth + 3*262144, Wtl, bo, bo, bo, nullptr, (float*)d_out);
}

// Round 14
// 308.849 us; speedup vs baseline: 1.5376x; 1.5376x over previous
//
#include <hip/hip_runtime.h>
#include <hip/hip_bf16.h>
#include <stdint.h>

#define SEQ    2048
#define DMODEL 512
#define NPANEL 16
#define NORM   0.044194173824159216f  // 1/sqrt(512)

typedef _Float16 f16;
typedef __attribute__((ext_vector_type(8))) _Float16 half8;
typedef __attribute__((ext_vector_type(2))) _Float16 half2v;
typedef __attribute__((ext_vector_type(4))) float f32x4;
typedef __attribute__((ext_vector_type(4))) unsigned int u32x4;

__device__ __forceinline__ unsigned umin2(unsigned a, unsigned b){ return a<b?a:b; }
__device__ __forceinline__ unsigned umax2(unsigned a, unsigned b){ return a>b?a:b; }

// ---------------- K0a: x,y fp32 -> fp16 hi+lo planes ----------------
__global__ __launch_bounds__(256) void k_cvt(const float4* __restrict__ x,
                                             const float4* __restrict__ y,
                                             f16* __restrict__ xh, f16* __restrict__ xl,
                                             f16* __restrict__ yh, f16* __restrict__ yl){
  int i = blockIdx.x*256 + threadIdx.x;      // 524288 float4s per tensor
  float4 a = x[i]; float4 b = y[i];
  half2v h0 = {(f16)a.x, (f16)a.y}, h1 = {(f16)a.z, (f16)a.w};
  *(half2v*)(xh + i*4)     = h0; *(half2v*)(xh + i*4 + 2) = h1;
  half2v l0 = {(f16)(a.x-(float)h0[0]), (f16)(a.y-(float)h0[1])};
  half2v l1 = {(f16)(a.z-(float)h1[0]), (f16)(a.w-(float)h1[1])};
  *(half2v*)(xl + i*4)     = l0; *(half2v*)(xl + i*4 + 2) = l1;
  half2v g0 = {(f16)b.x, (f16)b.y}, g1 = {(f16)b.z, (f16)b.w};
  *(half2v*)(yh + i*4)     = g0; *(half2v*)(yh + i*4 + 2) = g1;
  half2v m0 = {(f16)(b.x-(float)g0[0]), (f16)(b.y-(float)g0[1])};
  half2v m1 = {(f16)(b.z-(float)g1[0]), (f16)(b.w-(float)g1[1])};
  *(half2v*)(yl + i*4)     = m0; *(half2v*)(yl + i*4 + 2) = m1;
}

// ---------------- K0b: weights -> transposed fp16 hi+lo: Wt[z][n][k] ----------------
__global__ __launch_bounds__(256) void k_wt(const float* __restrict__ Wq, const float* __restrict__ Wk,
                                            const float* __restrict__ Wv, const float* __restrict__ Wo,
                                            f16* __restrict__ Wth, f16* __restrict__ Wtl){
  int z = blockIdx.z;
  const float* W = (z==0)?Wq:(z==1)?Wk:(z==2)?Wv:Wo;
  __shared__ float tile[64][65];
  int k0 = blockIdx.x*64, n0 = blockIdx.y*64;
  #pragma unroll
  for (int i = 0; i < 16; ++i){
    int s = threadIdx.x + i*256; int kl2 = s>>6, nl = s&63;
    tile[kl2][nl] = W[(k0+kl2)*512 + (n0+nl)];
  }
  __syncthreads();
  #pragma unroll
  for (int i = 0; i < 16; ++i){
    int s = threadIdx.x + i*256; int nl = s>>6, kl2 = s&63;
    float v = tile[kl2][nl];
    f16 h = (f16)v;
    int idx = z*262144 + (n0+nl)*512 + (k0+kl2);
    Wth[idx] = h;
    Wtl[idx] = (f16)(v - (float)h);
  }
}

// ---------------- GEMM: C[m,n] = A[m,:] @ Wt[n,:]^T + bias ----------------
template<int FINAL>
__global__ __launch_bounds__(256) void k_gemm(const f16* __restrict__ Ah0, const f16* __restrict__ Al0,
                                              const f16* __restrict__ Ah1, const f16* __restrict__ Al1,
                                              const f16* __restrict__ Wh, const f16* __restrict__ Wl,
                                              const float* __restrict__ b0, const float* __restrict__ b1,
                                              const float* __restrict__ b2,
                                              f16* __restrict__ Oq, float* __restrict__ Of){
  int z = blockIdx.z;
  const f16* A  = (z==0) ? Ah0 : Ah1;
  const f16* Alp= (z==0) ? Al0 : Al1;
  const f16* Bh = Wh + z*262144;
  const f16* Bl = Wl + z*262144;
  const float* bias = (z==0)?b0:(z==1)?b1:b2;
  const bool split = (FINAL==0) && (z<2);
  int m0 = blockIdx.x*128, n0 = blockIdx.y*128;

  __shared__ f16 Ahs[128][40], Bhs[128][40], Als[128][40], Bls[128][40];

  int t = threadIdx.x, l = t&63, w = t>>6;
  int wr = w>>1, wc = w&1;
  int lr = l&15, lk = l>>4;

  f32x4 acc[4][4];
  #pragma unroll
  for (int i=0;i<4;++i)
    #pragma unroll
    for (int j=0;j<4;++j) acc[i][j] = (f32x4){0.f,0.f,0.f,0.f};

  for (int ks = 0; ks < 16; ++ks){
    int k0 = ks*32;
    #pragma unroll
    for (int i = 0; i < 2; ++i){
      int s = t + i*256; int r = s>>2, kc = s&3;
      *(u32x4*)(&Ahs[r][kc*8]) = *(const u32x4*)(A   + (m0+r)*512 + k0 + kc*8);
      *(u32x4*)(&Bhs[r][kc*8]) = *(const u32x4*)(Bh  + (n0+r)*512 + k0 + kc*8);
      if (split){
        *(u32x4*)(&Als[r][kc*8]) = *(const u32x4*)(Alp + (m0+r)*512 + k0 + kc*8);
        *(u32x4*)(&Bls[r][kc*8]) = *(const u32x4*)(Bl  + (n0+r)*512 + k0 + kc*8);
      }
    }
    __syncthreads();
    half8 ah[4], bh2[4], al2[4], bl2[4];
    #pragma unroll
    for (int tm = 0; tm < 4; ++tm) ah[tm]  = *(const half8*)(&Ahs[wr*64 + tm*16 + lr][lk*8]);
    #pragma unroll
    for (int tn = 0; tn < 4; ++tn) bh2[tn] = *(const half8*)(&Bhs[wc*64 + tn*16 + lr][lk*8]);
    if (split){
      #pragma unroll
      for (int tm = 0; tm < 4; ++tm) al2[tm] = *(const half8*)(&Als[wr*64 + tm*16 + lr][lk*8]);
      #pragma unroll
      for (int tn = 0; tn < 4; ++tn) bl2[tn] = *(const half8*)(&Bls[wc*64 + tn*16 + lr][lk*8]);
    }
    #pragma unroll
    for (int tm = 0; tm < 4; ++tm)
      #pragma unroll
      for (int tn = 0; tn < 4; ++tn){
        acc[tm][tn] = __builtin_amdgcn_mfma_f32_16x16x32_f16(ah[tm], bh2[tn], acc[tm][tn], 0,0,0);
        if (split){
          acc[tm][tn] = __builtin_amdgcn_mfma_f32_16x16x32_f16(ah[tm], bl2[tn], acc[tm][tn], 0,0,0);
          acc[tm][tn] = __builtin_amdgcn_mfma_f32_16x16x32_f16(al2[tm], bh2[tn], acc[tm][tn], 0,0,0);
        }
      }
    __syncthreads();
  }

  #pragma unroll
  for (int tn = 0; tn < 4; ++tn){
    int n_g = n0 + wc*64 + tn*16 + lr;
    float bv = bias[n_g];
    #pragma unroll
    for (int tm = 0; tm < 4; ++tm){
      #pragma unroll
      for (int r = 0; r < 4; ++r){
        int m_g = m0 + wr*64 + tm*16 + lk*4 + r;
        float v = acc[tm][tn][r] + bv;
        size_t idx = (size_t)m_g*512 + n_g;
        if (FINAL){
          Of[idx] = v;
        } else if (z < 2){
          f16 h = (f16)v;
          Oq[(size_t)z*4194304 + idx] = h;
          Oq[(size_t)z*4194304 + 2097152 + idx] = (f16)(v - (float)h);
        } else {
          Oq[(size_t)4*2097152 + idx] = (f16)v;
        }
      }
    }
  }
}

// ---------------- K2: V panels [s][d] -> Vt [d][s] (fp16, bit-copy) ----------------
__global__ __launch_bounds__(256) void k_vt(const unsigned short* __restrict__ V, unsigned short* __restrict__ Vt){
  int p = blockIdx.y;
  int t = threadIdx.x;
  int d = t & 63, sc = t >> 6;
  int s0b = blockIdx.x*32 + sc*8;
  const unsigned short* Vp = V + p*131072;
  unsigned short* Vtp = Vt + p*131072;
  typedef __attribute__((ext_vector_type(8))) short short8;
  short8 vv;
  #pragma unroll
  for (int j = 0; j < 8; ++j) vv[j] = (short)Vp[(s0b + j)*64 + d];
  *(short8*)(Vtp + d*2048 + s0b) = vv;
}

// ---------------- K3: fused attention, 32 q-rows/WG (2x K/V reuse), XCD grid ----------------
// grid (16 panels fastest, 64 q-tiles of 32 rows), 1024 threads (16 waves), dyn LDS 131072 B.
// LDS: scores [32 rows][1024 f32] per col-phase; later P [32][2048 f16] in same region.
__global__ __launch_bounds__(1024, 4) void k_attn(const f16* __restrict__ Qh, const f16* __restrict__ Ql,
                                                  const f16* __restrict__ Kh, const f16* __restrict__ Kl,
                                                  const f16* __restrict__ Vt, f16* __restrict__ O){
  extern __shared__ char scb[];            // 131072
  __shared__ float rzs[32];
  __shared__ float red[6144];              // [3 quarters][2 rt][16 r][64 col] = 24KB
  int p = blockIdx.x, qt = blockIdx.y;     // panel fastest -> XCD affinity
  int s0 = qt*32;
  const f16* Qhp = Qh + p*131072;
  const f16* Qlp = Ql + p*131072;
  const f16* Khp = Kh + p*131072;
  const f16* Klp = Kl + p*131072;
  const f16* Vtp = Vt + p*131072;
  int t = threadIdx.x, l = t&63, w = t>>6;   // w in 0..15
  int lr = l&15, lk = l>>4;

  // Q fragments for rows s0 + rt*16 + lr
  half8 qh[2][2], qlo[2][2];
  #pragma unroll
  for (int rt = 0; rt < 2; ++rt)
    #pragma unroll
    for (int f = 0; f < 2; ++f){
      qh[rt][f]  = *(const half8*)(Qhp + (s0 + rt*16 + lr)*64 + f*32 + lk*8);
      qlo[rt][f] = *(const half8*)(Qlp + (s0 + rt*16 + lr)*64 + f*32 + lk*8);
    }

  unsigned ovA0[16], ovA1[16];

  // ---- Phase A: cols [w*64, +64) (global cols 0..1023); K loaded once per ct, used by 2 row-tiles ----
  {
    const f16* Kb = Khp + (w*64 + lr)*64 + lk*8;
    const f16* Lb = Klp + (w*64 + lr)*64 + lk*8;
    #pragma unroll
    for (int ct = 0; ct < 4; ++ct){
      const f16* ka = Kb + ct*1024;
      const f16* la = Lb + ct*1024;
      half8 kb0 = *(const half8*)(ka);
      half8 kb1 = *(const half8*)(ka + 32);
      half8 lb0 = *(const half8*)(la);
      half8 lb1 = *(const half8*)(la + 32);
      #pragma unroll
      for (int rt = 0; rt < 2; ++rt){
        f32x4 c1 = (f32x4){0.f,0.f,0.f,0.f};
        f32x4 c2 = (f32x4){0.f,0.f,0.f,0.f};
        f32x4 c3 = (f32x4){0.f,0.f,0.f,0.f};
        c1 = __builtin_amdgcn_mfma_f32_16x16x32_f16(qh[rt][0],  kb0, c1, 0,0,0);
        c2 = __builtin_amdgcn_mfma_f32_16x16x32_f16(qh[rt][0],  lb0, c2, 0,0,0);
        c3 = __builtin_amdgcn_mfma_f32_16x16x32_f16(qlo[rt][0], kb0, c3, 0,0,0);
        c1 = __builtin_amdgcn_mfma_f32_16x16x32_f16(qh[rt][1],  kb1, c1, 0,0,0);
        c2 = __builtin_amdgcn_mfma_f32_16x16x32_f16(qh[rt][1],  lb1, c2, 0,0,0);
        c3 = __builtin_amdgcn_mfma_f32_16x16x32_f16(qlo[rt][1], kb1, c3, 0,0,0);
        int n = w*64 + ct*16 + lr;
        #pragma unroll
        for (int r = 0; r < 4; ++r){
          int row = rt*16 + lk*4 + r;
          *(float*)(scb + row*4096 + (((unsigned)(n*4)) ^ ((unsigned)(lk<<6)))) = c1[r] + c2[r] + c3[r];
        }
      }
    }
  }
  __syncthreads();

  // persist phase-A ordered uints: wave w owns rows w and w+16
  {
    unsigned C = ((unsigned)((w>>2)&3))<<6;
    const char* rb0 = scb + w*4096;
    const char* rb1 = scb + (w+16)*4096;
    #pragma unroll
    for (int j = 0; j < 16; ++j){
      unsigned off = (((unsigned)((l + j*64)*4)) ^ C);
      unsigned u0 = *(const unsigned*)(rb0 + off);
      unsigned u1 = *(const unsigned*)(rb1 + off);
      ovA0[j] = ((int)u0 < 0) ? ~u0 : (u0 | 0x80000000u);
      ovA1[j] = ((int)u1 < 0) ? ~u1 : (u1 | 0x80000000u);
    }
  }
  __syncthreads();

  // ---- Phase B: cols 1024 + [w*64, +64) ----
  {
    const f16* Kb = Khp + (1024 + w*64 + lr)*64 + lk*8;
    const f16* Lb = Klp + (1024 + w*64 + lr)*64 + lk*8;
    #pragma unroll
    for (int ct = 0; ct < 4; ++ct){
      const f16* ka = Kb + ct*1024;
      const f16* la = Lb + ct*1024;
      half8 kb0 = *(const half8*)(ka);
      half8 kb1 = *(const half8*)(ka + 32);
      half8 lb0 = *(const half8*)(la);
      half8 lb1 = *(const half8*)(la + 32);
      #pragma unroll
      for (int rt = 0; rt < 2; ++rt){
        f32x4 c1 = (f32x4){0.f,0.f,0.f,0.f};
        f32x4 c2 = (f32x4){0.f,0.f,0.f,0.f};
        f32x4 c3 = (f32x4){0.f,0.f,0.f,0.f};
        c1 = __builtin_amdgcn_mfma_f32_16x16x32_f16(qh[rt][0],  kb0, c1, 0,0,0);
        c2 = __builtin_amdgcn_mfma_f32_16x16x32_f16(qh[rt][0],  lb0, c2, 0,0,0);
        c3 = __builtin_amdgcn_mfma_f32_16x16x32_f16(qlo[rt][0], kb0, c3, 0,0,0);
        c1 = __builtin_amdgcn_mfma_f32_16x16x32_f16(qh[rt][1],  kb1, c1, 0,0,0);
        c2 = __builtin_amdgcn_mfma_f32_16x16x32_f16(qh[rt][1],  lb1, c2, 0,0,0);
        c3 = __builtin_amdgcn_mfma_f32_16x16x32_f16(qlo[rt][1], kb1, c3, 0,0,0);
        int n = w*64 + ct*16 + lr;
        #pragma unroll
        for (int r = 0; r < 4; ++r){
          int row = rt*16 + lk*4 + r;
          *(float*)(scb + row*4096 + (((unsigned)(n*4)) ^ ((unsigned)(lk<<6)))) = c1[r] + c2[r] + c3[r];
        }
      }
    }
  }
  __syncthreads();

  // ---- selection + softmax weights: wave w owns rows w and w+16 (round-3 flow) ----
  #pragma unroll 1
  for (int rr = 0; rr < 2; ++rr){
    int row = w + rr*16;
    const char* rb = scb + row*4096;
    unsigned C = ((unsigned)((w>>2)&3))<<6;
    unsigned o2[16];
    #pragma unroll
    for (int j = 0; j < 16; ++j){
      unsigned u = *(const unsigned*)(rb + (((unsigned)((l + j*64)*4)) ^ C));
      o2[j] = ((int)u < 0) ? ~u : (u | 0x80000000u);
    }
    unsigned umn = 0xFFFFFFFFu, umx = 0u;
    #pragma unroll
    for (int j = 0; j < 16; ++j){
      unsigned a = (rr==0) ? ovA0[j] : ovA1[j];
      umn = umin2(umn, umin2(a, o2[j]));
      umx = umax2(umax2(umx, a), o2[j]);
    }
    #pragma unroll
    for (int off2 = 1; off2 < 64; off2 <<= 1){
      umn = umin2(umn, (unsigned)__shfl_xor((int)umn, off2));
      umx = umax2(umx, (unsigned)__shfl_xor((int)umx, off2));
    }
    unsigned thr;
    {
      unsigned L = umn, R = umx;
      #pragma unroll 1
      for (;;){
        if (L >= R){ thr = R; break; }
        unsigned mid = L + ((R - L) >> 1);
        int c = 0;
        #pragma unroll
        for (int j = 0; j < 16; ++j){
          unsigned a = (rr==0) ? ovA0[j] : ovA1[j];
          c += (int)__popcll(__ballot(a <= mid));
          c += (int)__popcll(__ballot(o2[j] <= mid));
        }
        if (c == 1024){ thr = mid; break; }
        if (c > 1024) R = mid; else L = mid + 1;
      }
    }
    unsigned bmx = (umx & 0x80000000u) ? (umx & 0x7FFFFFFFu) : ~umx;
    float mx = __uint_as_float(bmx);
    float zs = 0.f;
    unsigned g = ((unsigned)(row & 7)) << 4;
    char* pb = scb + row*4096;
    #pragma unroll
    for (int j = 0; j < 32; ++j){
      unsigned a = (j < 16) ? ((rr==0) ? ovA0[j] : ovA1[j]) : o2[j-16];
      unsigned b = (a & 0x80000000u) ? (a & 0x7FFFFFFFu) : ~a;
      float v = __uint_as_float(b);
      float wgt = (a <= thr) ? 0.f : __expf((v - mx) * NORM);
      zs += wgt;
      unsigned col = (unsigned)((j & 15)*64 + l + (j >> 4)*1024);
      *(f16*)(pb + ((col*2) ^ g)) = (f16)wgt;
    }
    #pragma unroll
    for (int off2 = 1; off2 < 64; off2 <<= 1) zs += __shfl_xor(zs, off2);
    if (l == 0) rzs[row] = 1.f / zs;
  }
  __syncthreads();

  // ---- PV: wave -> out-col tile oc = w&3, K-quarter q = w>>2 (512 wide); both row-tiles ----
  int oc = w & 3, q = w >> 2;
  const f16* vbase = Vtp + (oc*16 + lr)*2048 + q*512 + lk*8;
  unsigned pswz = ((unsigned)(lr & 7)) << 4;
  f32x4 a00 = (f32x4){0.f,0.f,0.f,0.f};
  f32x4 a01 = (f32x4){0.f,0.f,0.f,0.f};
  f32x4 a10 = (f32x4){0.f,0.f,0.f,0.f};
  f32x4 a11 = (f32x4){0.f,0.f,0.f,0.f};
  #pragma unroll 4
  for (int kc = 0; kc < 16; ++kc){
    half8 vb = *(const half8*)(vbase + kc*32);
    unsigned poff = (((unsigned)((q*512 + kc*32 + lk*8)*2)) ^ pswz);
    half8 pa0 = *(const half8*)(scb + lr*4096 + poff);
    half8 pa1 = *(const half8*)(scb + (16 + lr)*4096 + poff);
    if (kc & 1){
      a01 = __builtin_amdgcn_mfma_f32_16x16x32_f16(pa0, vb, a01, 0,0,0);
      a11 = __builtin_amdgcn_mfma_f32_16x16x32_f16(pa1, vb, a11, 0,0,0);
    } else {
      a00 = __builtin_amdgcn_mfma_f32_16x16x32_f16(pa0, vb, a00, 0,0,0);
      a10 = __builtin_amdgcn_mfma_f32_16x16x32_f16(pa1, vb, a10, 0,0,0);
    }
  }
  f32x4 oa[2];
  #pragma unroll
  for (int r = 0; r < 4; ++r){ oa[0][r] = a00[r] + a01[r]; oa[1][r] = a10[r] + a11[r]; }
  if (q > 0){
    #pragma unroll
    for (int rt = 0; rt < 2; ++rt)
      #pragma unroll
      for (int r = 0; r < 4; ++r)
        red[(q-1)*2048 + rt*1024 + (lk*4+r)*64 + oc*16 + lr] = oa[rt][r];
  }
  __syncthreads();
  if (q == 0){
    #pragma unroll
    for (int rt = 0; rt < 2; ++rt)
      #pragma unroll
      for (int r = 0; r < 4; ++r){
        int row = rt*16 + lk*4 + r;
        int ci = rt*1024 + (lk*4+r)*64 + oc*16 + lr;
        float v = (oa[rt][r] + red[ci] + red[2048 + ci] + red[4096 + ci]) * rzs[row];
        O[p*131072 + (s0+row)*64 + oc*16 + lr] = (f16)v;
      }
  }
}

// ---------------- host ----------------
extern "C" void kernel_launch(void* const* d_in, const int* in_sizes, int n_in,
                              void* d_out, int out_size, void* d_ws, size_t ws_size,
                              hipStream_t stream) {
  const float* x  = (const float*)d_in[0];
  const float* y  = (const float*)d_in[1];
  const float* Wq = (const float*)d_in[2];
  const float* bq = (const float*)d_in[3];
  const float* Wk = (const float*)d_in[4];
  const float* bk = (const float*)d_in[5];
  const float* Wv = (const float*)d_in[6];
  const float* bv = (const float*)d_in[7];
  const float* Wo = (const float*)d_in[8];
  const float* bo = (const float*)d_in[9];

  f16* ws = (f16*)d_ws;
  f16* xh  = ws;                    // 2097152 each
  f16* xl  = ws + 2097152;
  f16* yh  = ws + 4194304;
  f16* yl  = ws + 6291456;
  f16* Wth = ws + 8388608;          // 4 x 262144
  f16* Wtl = ws + 9437184;
  f16* QKV = ws + 10485760;         // Qh,Ql,Kh,Kl,Vh : 5 x 2097152
  f16* Vt  = ws;                    // alias xh (dead after QKV gemm)
  f16* Ob  = ws + 2097152;          // alias xl (dead after QKV gemm)

  (void)hipFuncSetAttribute(reinterpret_cast<const void*>(k_attn),
                            hipFuncAttributeMaxDynamicSharedMemorySize, 131072);

  k_cvt<<<2048, 256, 0, stream>>>((const float4*)x, (const float4*)y, xh, xl, yh, yl);
  k_wt<<<dim3(8,8,4), 256, 0, stream>>>(Wq, Wk, Wv, Wo, Wth, Wtl);
  k_gemm<0><<<dim3(32,4,3), 256, 0, stream>>>(xh, xl, yh, yl, Wth, Wtl, bq, bk, bv, QKV, nullptr);
  k_vt<<<dim3(64,16), 256, 0, stream>>>((const unsigned short*)(QKV + 4*2097152), (unsigned short*)Vt);
  k_attn<<<dim3(16,64), 1024, 131072, stream>>>(QKV, QKV + 2097152, QKV + 2*2097152, QKV + 3*2097152, Vt, Ob);
  k_gemm<1><<<dim3(32,4,1), 256, 0, stream>>>(Ob, Ob, Ob, Ob, Wth + 3*262144, Wtl, bo, bo, bo, nullptr, (float*)d_out);
}

// Round 15
// 286.929 us; speedup vs baseline: 1.6551x; 1.0764x over previous
//
#include <hip/hip_runtime.h>
#include <hip/hip_bf16.h>
#include <stdint.h>

#define SEQ    2048
#define DMODEL 512
#define NPANEL 16
#define NORM   0.044194173824159216f  // 1/sqrt(512)

typedef _Float16 f16;
typedef __attribute__((ext_vector_type(8))) _Float16 half8;
typedef __attribute__((ext_vector_type(2))) _Float16 half2v;
typedef __attribute__((ext_vector_type(4))) float f32x4;
typedef __attribute__((ext_vector_type(4))) unsigned int u32x4;

__device__ __forceinline__ unsigned umin2(unsigned a, unsigned b){ return a<b?a:b; }
__device__ __forceinline__ unsigned umax2(unsigned a, unsigned b){ return a>b?a:b; }

// ---------------- K0a: x,y fp32 -> fp16 hi+lo planes ----------------
__global__ __launch_bounds__(256) void k_cvt(const float4* __restrict__ x,
                                             const float4* __restrict__ y,
                                             f16* __restrict__ xh, f16* __restrict__ xl,
                                             f16* __restrict__ yh, f16* __restrict__ yl){
  int i = blockIdx.x*256 + threadIdx.x;      // 524288 float4s per tensor
  float4 a = x[i]; float4 b = y[i];
  half2v h0 = {(f16)a.x, (f16)a.y}, h1 = {(f16)a.z, (f16)a.w};
  *(half2v*)(xh + i*4)     = h0; *(half2v*)(xh + i*4 + 2) = h1;
  half2v l0 = {(f16)(a.x-(float)h0[0]), (f16)(a.y-(float)h0[1])};
  half2v l1 = {(f16)(a.z-(float)h1[0]), (f16)(a.w-(float)h1[1])};
  *(half2v*)(xl + i*4)     = l0; *(half2v*)(xl + i*4 + 2) = l1;
  half2v g0 = {(f16)b.x, (f16)b.y}, g1 = {(f16)b.z, (f16)b.w};
  *(half2v*)(yh + i*4)     = g0; *(half2v*)(yh + i*4 + 2) = g1;
  half2v m0 = {(f16)(b.x-(float)g0[0]), (f16)(b.y-(float)g0[1])};
  half2v m1 = {(f16)(b.z-(float)g1[0]), (f16)(b.w-(float)g1[1])};
  *(half2v*)(yl + i*4)     = m0; *(half2v*)(yl + i*4 + 2) = m1;
}

// ---------------- K0b: weights -> transposed fp16 hi+lo: Wt[z][n][k] ----------------
__global__ __launch_bounds__(256) void k_wt(const float* __restrict__ Wq, const float* __restrict__ Wk,
                                            const float* __restrict__ Wv, const float* __restrict__ Wo,
                                            f16* __restrict__ Wth, f16* __restrict__ Wtl){
  int z = blockIdx.z;
  const float* W = (z==0)?Wq:(z==1)?Wk:(z==2)?Wv:Wo;
  __shared__ float tile[64][65];
  int k0 = blockIdx.x*64, n0 = blockIdx.y*64;
  #pragma unroll
  for (int i = 0; i < 16; ++i){
    int s = threadIdx.x + i*256; int kl2 = s>>6, nl = s&63;
    tile[kl2][nl] = W[(k0+kl2)*512 + (n0+nl)];
  }
  __syncthreads();
  #pragma unroll
  for (int i = 0; i < 16; ++i){
    int s = threadIdx.x + i*256; int nl = s>>6, kl2 = s&63;
    float v = tile[kl2][nl];
    f16 h = (f16)v;
    int idx = z*262144 + (n0+nl)*512 + (k0+kl2);
    Wth[idx] = h;
    Wtl[idx] = (f16)(v - (float)h);
  }
}

// ---------------- GEMM: C[m,n] = A[m,:] @ Wt[n,:]^T + bias ----------------
template<int FINAL>
__global__ __launch_bounds__(256) void k_gemm(const f16* __restrict__ Ah0, const f16* __restrict__ Al0,
                                              const f16* __restrict__ Ah1, const f16* __restrict__ Al1,
                                              const f16* __restrict__ Wh, const f16* __restrict__ Wl,
                                              const float* __restrict__ b0, const float* __restrict__ b1,
                                              const float* __restrict__ b2,
                                              f16* __restrict__ Oq, float* __restrict__ Of){
  int z = blockIdx.z;
  const f16* A  = (z==0) ? Ah0 : Ah1;
  const f16* Alp= (z==0) ? Al0 : Al1;
  const f16* Bh = Wh + z*262144;
  const f16* Bl = Wl + z*262144;
  const float* bias = (z==0)?b0:(z==1)?b1:b2;
  const bool split = (FINAL==0) && (z<2);
  int m0 = blockIdx.x*128, n0 = blockIdx.y*128;

  __shared__ f16 Ahs[128][40], Bhs[128][40], Als[128][40], Bls[128][40];

  int t = threadIdx.x, l = t&63, w = t>>6;
  int wr = w>>1, wc = w&1;
  int lr = l&15, lk = l>>4;

  f32x4 acc[4][4];
  #pragma unroll
  for (int i=0;i<4;++i)
    #pragma unroll
    for (int j=0;j<4;++j) acc[i][j] = (f32x4){0.f,0.f,0.f,0.f};

  for (int ks = 0; ks < 16; ++ks){
    int k0 = ks*32;
    #pragma unroll
    for (int i = 0; i < 2; ++i){
      int s = t + i*256; int r = s>>2, kc = s&3;
      *(u32x4*)(&Ahs[r][kc*8]) = *(const u32x4*)(A   + (m0+r)*512 + k0 + kc*8);
      *(u32x4*)(&Bhs[r][kc*8]) = *(const u32x4*)(Bh  + (n0+r)*512 + k0 + kc*8);
      if (split){
        *(u32x4*)(&Als[r][kc*8]) = *(const u32x4*)(Alp + (m0+r)*512 + k0 + kc*8);
        *(u32x4*)(&Bls[r][kc*8]) = *(const u32x4*)(Bl  + (n0+r)*512 + k0 + kc*8);
      }
    }
    __syncthreads();
    half8 ah[4], bh2[4], al2[4], bl2[4];
    #pragma unroll
    for (int tm = 0; tm < 4; ++tm) ah[tm]  = *(const half8*)(&Ahs[wr*64 + tm*16 + lr][lk*8]);
    #pragma unroll
    for (int tn = 0; tn < 4; ++tn) bh2[tn] = *(const half8*)(&Bhs[wc*64 + tn*16 + lr][lk*8]);
    if (split){
      #pragma unroll
      for (int tm = 0; tm < 4; ++tm) al2[tm] = *(const half8*)(&Als[wr*64 + tm*16 + lr][lk*8]);
      #pragma unroll
      for (int tn = 0; tn < 4; ++tn) bl2[tn] = *(const half8*)(&Bls[wc*64 + tn*16 + lr][lk*8]);
    }
    #pragma unroll
    for (int tm = 0; tm < 4; ++tm)
      #pragma unroll
      for (int tn = 0; tn < 4; ++tn){
        acc[tm][tn] = __builtin_amdgcn_mfma_f32_16x16x32_f16(ah[tm], bh2[tn], acc[tm][tn], 0,0,0);
        if (split){
          acc[tm][tn] = __builtin_amdgcn_mfma_f32_16x16x32_f16(ah[tm], bl2[tn], acc[tm][tn], 0,0,0);
          acc[tm][tn] = __builtin_amdgcn_mfma_f32_16x16x32_f16(al2[tm], bh2[tn], acc[tm][tn], 0,0,0);
        }
      }
    __syncthreads();
  }

  #pragma unroll
  for (int tn = 0; tn < 4; ++tn){
    int n_g = n0 + wc*64 + tn*16 + lr;
    float bv = bias[n_g];
    #pragma unroll
    for (int tm = 0; tm < 4; ++tm){
      #pragma unroll
      for (int r = 0; r < 4; ++r){
        int m_g = m0 + wr*64 + tm*16 + lk*4 + r;
        float v = acc[tm][tn][r] + bv;
        size_t idx = (size_t)m_g*512 + n_g;
        if (FINAL){
          Of[idx] = v;
        } else if (z < 2){
          f16 h = (f16)v;
          Oq[(size_t)z*4194304 + idx] = h;
          Oq[(size_t)z*4194304 + 2097152 + idx] = (f16)(v - (float)h);
        } else {
          Oq[(size_t)4*2097152 + idx] = (f16)v;
        }
      }
    }
  }
}

// ---------------- K2: V panels [s][d] -> Vt [d][s] (fp16, bit-copy) ----------------
__global__ __launch_bounds__(256) void k_vt(const unsigned short* __restrict__ V, unsigned short* __restrict__ Vt){
  int p = blockIdx.y;
  int t = threadIdx.x;
  int d = t & 63, sc = t >> 6;
  int s0b = blockIdx.x*32 + sc*8;
  const unsigned short* Vp = V + p*131072;
  unsigned short* Vtp = Vt + p*131072;
  typedef __attribute__((ext_vector_type(8))) short short8;
  short8 vv;
  #pragma unroll
  for (int j = 0; j < 8; ++j) vv[j] = (short)Vp[(s0b + j)*64 + d];
  *(short8*)(Vtp + d*2048 + s0b) = vv;
}

// ---------------- K3: fused attention (round-11 algorithm, ROLLED loops / small code) ----------------
// grid (16 panels fastest, 128 q-tiles), 512 threads, dynamic LDS 65536 B (2 WGs/CU)
__global__ __launch_bounds__(512, 4) void k_attn(const f16* __restrict__ Qh, const f16* __restrict__ Ql,
                                                 const f16* __restrict__ Kh, const f16* __restrict__ Kl,
                                                 const f16* __restrict__ Vt, f16* __restrict__ O){
  extern __shared__ char scb[];            // 65536
  __shared__ float rzs[16];
  __shared__ float red[1024];
  int p = blockIdx.x, qt = blockIdx.y;     // panel fastest -> XCD affinity
  int s0 = qt*16;
  const f16* Qhp = Qh + p*131072;
  const f16* Qlp = Ql + p*131072;
  const f16* Khp = Kh + p*131072;
  const f16* Klp = Kl + p*131072;
  const f16* Vtp = Vt + p*131072;
  int t = threadIdx.x, l = t&63, w = t>>6;
  int lr = l&15, lk = l>>4;

  half8 qh[2], ql[2];
  #pragma unroll
  for (int f = 0; f < 2; ++f){
    qh[f] = *(const half8*)(Qhp + (s0+lr)*64 + f*32 + lk*8);
    ql[f] = *(const half8*)(Qlp + (s0+lr)*64 + f*32 + lk*8);
  }

  unsigned ovA0[16], ovA1[16];

  // ---- QK^T: two col-phases, rolled ct loop (small code footprint) ----
  #pragma unroll 1
  for (int ph = 0; ph < 2; ++ph){
    const f16* ka = Khp + ((ph<<10) + w*128 + lr)*64 + lk*8;
    const f16* la = Klp + ((ph<<10) + w*128 + lr)*64 + lk*8;
    int n = w*128 + lr;                    // phase-local col
    #pragma unroll 1
    for (int ct = 0; ct < 8; ++ct){
      half8 kb0 = *(const half8*)(ka);
      half8 kb1 = *(const half8*)(ka + 32);
      half8 lb0 = *(const half8*)(la);
      half8 lb1 = *(const half8*)(la + 32);
      f32x4 c1 = (f32x4){0.f,0.f,0.f,0.f};
      f32x4 c2 = (f32x4){0.f,0.f,0.f,0.f};
      f32x4 c3 = (f32x4){0.f,0.f,0.f,0.f};
      c1 = __builtin_amdgcn_mfma_f32_16x16x32_f16(qh[0], kb0, c1, 0,0,0);
      c2 = __builtin_amdgcn_mfma_f32_16x16x32_f16(qh[0], lb0, c2, 0,0,0);
      c3 = __builtin_amdgcn_mfma_f32_16x16x32_f16(ql[0], kb0, c3, 0,0,0);
      c1 = __builtin_amdgcn_mfma_f32_16x16x32_f16(qh[1], kb1, c1, 0,0,0);
      c2 = __builtin_amdgcn_mfma_f32_16x16x32_f16(qh[1], lb1, c2, 0,0,0);
      c3 = __builtin_amdgcn_mfma_f32_16x16x32_f16(ql[1], kb1, c3, 0,0,0);
      #pragma unroll
      for (int r = 0; r < 4; ++r){
        int row = lk*4 + r;
        *(float*)(scb + row*4096 + (((unsigned)(n*4)) ^ ((unsigned)(lk<<6)))) = c1[r] + c2[r] + c3[r];
      }
      ka += 1024; la += 1024; n += 16;
    }
    __syncthreads();
    if (ph == 0){
      // persist phase-A ordered uints for my two rows (2w, 2w+1)
      unsigned C = ((unsigned)((w>>1)&3))<<6;
      const char* rb0 = scb + (w*2)*4096;
      const char* rb1 = rb0 + 4096;
      #pragma unroll
      for (int j = 0; j < 16; ++j){
        unsigned off = (((unsigned)((l + j*64)*4)) ^ C);
        unsigned u0 = *(const unsigned*)(rb0 + off);
        unsigned u1 = *(const unsigned*)(rb1 + off);
        ovA0[j] = ((int)u0 < 0) ? ~u0 : (u0 | 0x80000000u);
        ovA1[j] = ((int)u1 < 0) ? ~u1 : (u1 | 0x80000000u);
      }
      __syncthreads();
    }
  }

  // ---- selection + softmax weights (wave w owns rows 2w, 2w+1) — round-3/11 flow ----
  #pragma unroll 1
  for (int rr = 0; rr < 2; ++rr){
    int row = w*2 + rr;
    const char* rb = scb + row*4096;
    unsigned C = ((unsigned)((row>>2)&3))<<6;
    unsigned o2[16];
    #pragma unroll
    for (int j = 0; j < 16; ++j){
      unsigned u = *(const unsigned*)(rb + (((unsigned)((l + j*64)*4)) ^ C));
      o2[j] = ((int)u < 0) ? ~u : (u | 0x80000000u);
    }
    unsigned umn = 0xFFFFFFFFu, umx = 0u;
    #pragma unroll
    for (int j = 0; j < 16; ++j){
      unsigned a = (rr==0) ? ovA0[j] : ovA1[j];
      umn = umin2(umn, umin2(a, o2[j]));
      umx = umax2(umax2(umx, a), o2[j]);
    }
    #pragma unroll
    for (int off2 = 1; off2 < 64; off2 <<= 1){
      umn = umin2(umn, (unsigned)__shfl_xor((int)umn, off2));
      umx = umax2(umx, (unsigned)__shfl_xor((int)umx, off2));
    }
    unsigned thr;
    {
      unsigned L = umn, R = umx;
      #pragma unroll 1
      for (;;){
        if (L >= R){ thr = R; break; }
        unsigned mid = L + ((R - L) >> 1);
        int c = 0;
        #pragma unroll
        for (int j = 0; j < 16; ++j){
          unsigned a = (rr==0) ? ovA0[j] : ovA1[j];
          c += (int)__popcll(__ballot(a <= mid));
          c += (int)__popcll(__ballot(o2[j] <= mid));
        }
        if (c == 1024){ thr = mid; break; }
        if (c > 1024) R = mid; else L = mid + 1;
      }
    }
    unsigned bmx = (umx & 0x80000000u) ? (umx & 0x7FFFFFFFu) : ~umx;
    float mx = __uint_as_float(bmx);
    float zs = 0.f;
    unsigned g = ((unsigned)(row & 7)) << 4;
    char* pb = scb + row*4096;
    #pragma unroll
    for (int j = 0; j < 32; ++j){
      unsigned a = (j < 16) ? ((rr==0) ? ovA0[j] : ovA1[j]) : o2[j-16];
      unsigned b = (a & 0x80000000u) ? (a & 0x7FFFFFFFu) : ~a;
      float v = __uint_as_float(b);
      float wgt = (a <= thr) ? 0.f : __expf((v - mx) * NORM);
      zs += wgt;
      unsigned col = (unsigned)((j & 15)*64 + l + (j >> 4)*1024);
      *(f16*)(pb + ((col*2) ^ g)) = (f16)wgt;
    }
    #pragma unroll
    for (int off2 = 1; off2 < 64; off2 <<= 1) zs += __shfl_xor(zs, off2);
    if (l == 0) rzs[row] = 1.f / zs;
  }
  __syncthreads();

  // ---- PV: wave: oc = w&3, kh2 = w>>2; rolled loop, 2 MFMAs/iter ----
  int oc = w & 3, kh2 = w >> 2;
  const f16* vb = Vtp + (oc*16 + lr)*2048 + kh2*1024 + lk*8;
  const char* pbase = scb + lr*4096;
  unsigned pswz = ((unsigned)(lr & 7)) << 4;
  unsigned pk = (unsigned)(kh2*1024 + lk*8);
  f32x4 o0 = (f32x4){0.f,0.f,0.f,0.f};
  f32x4 o1 = (f32x4){0.f,0.f,0.f,0.f};
  #pragma unroll 1
  for (int it = 0; it < 16; ++it){
    half8 pa0 = *(const half8*)(pbase + (((pk)*2) ^ pswz));
    half8 vb0 = *(const half8*)(vb);
    half8 pa1 = *(const half8*)(pbase + (((pk + 32)*2) ^ pswz));
    half8 vb1 = *(const half8*)(vb + 32);
    o0 = __builtin_amdgcn_mfma_f32_16x16x32_f16(pa0, vb0, o0, 0,0,0);
    o1 = __builtin_amdgcn_mfma_f32_16x16x32_f16(pa1, vb1, o1, 0,0,0);
    pk += 64; vb += 64;
  }
  f32x4 oa;
  #pragma unroll
  for (int r = 0; r < 4; ++r) oa[r] = o0[r] + o1[r];
  if (kh2 == 1){
    #pragma unroll
    for (int r = 0; r < 4; ++r) red[oc*256 + (lk*4+r)*16 + lr] = oa[r];
  }
  __syncthreads();
  if (kh2 == 0){
    #pragma unroll
    for (int r = 0; r < 4; ++r){
      int row = lk*4 + r;
      float v = (oa[r] + red[oc*256 + row*16 + lr]) * rzs[row];
      O[p*131072 + (s0+row)*64 + oc*16 + lr] = (f16)v;
    }
  }
}

// ---------------- host ----------------
extern "C" void kernel_launch(void* const* d_in, const int* in_sizes, int n_in,
                              void* d_out, int out_size, void* d_ws, size_t ws_size,
                              hipStream_t stream) {
  const float* x  = (const float*)d_in[0];
  const float* y  = (const float*)d_in[1];
  const float* Wq = (const float*)d_in[2];
  const float* bq = (const float*)d_in[3];
  const float* Wk = (const float*)d_in[4];
  const float* bk = (const float*)d_in[5];
  const float* Wv = (const float*)d_in[6];
  const float* bv = (const float*)d_in[7];
  const float* Wo = (const float*)d_in[8];
  const float* bo = (const float*)d_in[9];

  f16* ws = (f16*)d_ws;
  f16* xh  = ws;                    // 2097152 each
  f16* xl  = ws + 2097152;
  f16* yh  = ws + 4194304;
  f16* yl  = ws + 6291456;
  f16* Wth = ws + 8388608;          // 4 x 262144
  f16* Wtl = ws + 9437184;
  f16* QKV = ws + 10485760;         // Qh,Ql,Kh,Kl,Vh : 5 x 2097152
  f16* Vt  = ws;                    // alias xh (dead after QKV gemm)
  f16* Ob  = ws + 2097152;          // alias xl (dead after QKV gemm)

  (void)hipFuncSetAttribute(reinterpret_cast<const void*>(k_attn),
                            hipFuncAttributeMaxDynamicSharedMemorySize, 65536);

  k_cvt<<<2048, 256, 0, stream>>>((const float4*)x, (const float4*)y, xh, xl, yh, yl);
  k_wt<<<dim3(8,8,4), 256, 0, stream>>>(Wq, Wk, Wv, Wo, Wth, Wtl);
  k_gemm<0><<<dim3(32,4,3), 256, 0, stream>>>(xh, xl, yh, yl, Wth, Wtl, bq, bk, bv, QKV, nullptr);
  k_vt<<<dim3(64,16), 256, 0, stream>>>((const unsigned short*)(QKV + 4*2097152), (unsigned short*)Vt);
  k_attn<<<dim3(16,128), 512, 65536, stream>>>(QKV, QKV + 2097152, QKV + 2*2097152, QKV + 3*2097152, Vt, Ob);
  k_gemm<1><<<dim3(32,4,1), 256, 0, stream>>>(Ob, Ob, Ob, Ob, Wth + 3*262144, Wtl, bo, bo, bo, nullptr, (float*)d_out);
}